// Round 2
// baseline (2985.815 us; speedup 1.0000x reference)
//
#include <hip/hip_runtime.h>
#include <hip/hip_bf16.h>
#include <math.h>

#define B_  16
#define C_  1536
#define N_  1024
#define K_  64
#define D_  128
#define T_  256
#define OUTW (T_ + D_*K_)   // 8448

// ---------------- K1: token path (t_norm, gate softmax) ----------------
__global__ __launch_bounds__(256) void k_token(
    const float* __restrict__ token,
    const float* __restrict__ tf_w1, const float* __restrict__ tf_b1,
    const float* __restrict__ tf_w2, const float* __restrict__ tf_b2,
    const float* __restrict__ g_w1, const float* __restrict__ g_b1,
    const float* __restrict__ g_w2, const float* __restrict__ g_b2,
    float* __restrict__ t_norm, float* __restrict__ gw_out)
{
  const int b = blockIdx.x;
  const int t = threadIdx.x;
  const int wid = t >> 6, lane = t & 63;
  __shared__ float tok[C_];
  __shared__ float th1[512];
  __shared__ float tt[T_];
  __shared__ float gh[128];
  __shared__ float red[8];
  for (int i = t; i < C_; i += 256) tok[i] = token[b*C_ + i];
  __syncthreads();
  // th1[512] = relu(token @ tf_w1^T + b1), wave-cooperative dots (coalesced)
  for (int o = wid; o < 512; o += 4) {
    const float* wr = tf_w1 + (size_t)o*C_;
    float s = 0.f;
    for (int c = lane; c < C_; c += 64) s = fmaf(tok[c], wr[c], s);
    for (int off = 32; off; off >>= 1) s += __shfl_down(s, off);
    if (lane == 0) th1[o] = fmaxf(s + tf_b1[o], 0.f);
  }
  // gate hidden gh[128]
  for (int o = wid; o < 128; o += 4) {
    const float* wr = g_w1 + (size_t)o*C_;
    float s = 0.f;
    for (int c = lane; c < C_; c += 64) s = fmaf(tok[c], wr[c], s);
    for (int off = 32; off; off >>= 1) s += __shfl_down(s, off);
    if (lane == 0) gh[o] = fmaxf(s + g_b1[o], 0.f);
  }
  __syncthreads();
  // t[256] = th1 @ tf_w2^T + b2
  for (int o = wid; o < T_; o += 4) {
    const float* wr = tf_w2 + (size_t)o*512;
    float s = 0.f;
    for (int c = lane; c < 512; c += 64) s = fmaf(th1[c], wr[c], s);
    for (int off = 32; off; off >>= 1) s += __shfl_down(s, off);
    if (lane == 0) tt[o] = s + tf_b2[o];
  }
  __syncthreads();
  // gate output + softmax (E=2)
  if (t == 0) {
    float g0 = g_b2[0], g1 = g_b2[1];
    for (int j = 0; j < 128; j++) {
      g0 = fmaf(gh[j], g_w2[j], g0);
      g1 = fmaf(gh[j], g_w2[128 + j], g1);
    }
    float m = fmaxf(g0, g1);
    float e0 = __expf(g0 - m), e1 = __expf(g1 - m);
    float inv = 1.f / (e0 + e1);
    gw_out[b*2 + 0] = e0 * inv; gw_out[b*2 + 1] = e1 * inv;
  }
  // l2 normalize t (256 elems, one per thread)
  float vv = tt[t];
  float ss = vv * vv;
  for (int off = 32; off; off >>= 1) ss += __shfl_down(ss, off);
  if (lane == 0) red[wid] = ss;
  __syncthreads();
  if (t == 0) red[4] = 1.f / fmaxf(sqrtf(red[0]+red[1]+red[2]+red[3]), 1e-12f);
  __syncthreads();
  t_norm[b*T_ + t] = vv * red[4];
}

// ---------------- K2: GEMM1 [16384 x 1536] x [1536 stacked outputs], relu, bf16 out
// stacked rows: o<512 -> cf path (h1), o in [512,1536) -> experts (eh0|eh1)
__global__ __launch_bounds__(256) void k_gemm1(
    const float* __restrict__ x,
    const float* __restrict__ cf_w1, const float* __restrict__ cf_b1,
    const float* __restrict__ ex_w1, const float* __restrict__ ex_b1,
    __hip_bfloat16* __restrict__ h)
{
  const int b  = blockIdx.z;
  const int o0 = blockIdx.y * 64;
  const int n0 = blockIdx.x * 64;
  const int t  = threadIdx.x;
  const int ty = t >> 4, tx = t & 15;
  __shared__ __align__(16) float Ws[16][64];   // k-major
  __shared__ __align__(16) float Xs[16][64];
  float acc[4][4] = {};
  const float* __restrict__ xb = x + (size_t)b*C_*N_ + n0;
  const int wr = t >> 2, wc = (t & 3) * 4;     // W tile: row, col4
  const int xr = t >> 4, xc = (t & 15) * 4;    // X tile: row, col4
  const float* wrow = (o0 < 512) ? (cf_w1 + (size_t)(o0 + wr)*C_)
                                 : (ex_w1 + (size_t)(o0 - 512 + wr)*C_);
  for (int k0 = 0; k0 < C_; k0 += 16) {
    float4 wv = *(const float4*)(wrow + k0 + wc);
    float4 xv = *(const float4*)(xb + (size_t)(k0 + xr)*N_ + xc);
    Ws[wc+0][wr] = wv.x; Ws[wc+1][wr] = wv.y; Ws[wc+2][wr] = wv.z; Ws[wc+3][wr] = wv.w;
    *(float4*)&Xs[xr][xc] = xv;
    __syncthreads();
    #pragma unroll
    for (int kk = 0; kk < 16; kk++) {
      float4 av = *(const float4*)&Ws[kk][ty*4];
      float4 bv = *(const float4*)&Xs[kk][tx*4];
      float aa[4] = {av.x, av.y, av.z, av.w};
      float bb[4] = {bv.x, bv.y, bv.z, bv.w};
      #pragma unroll
      for (int i = 0; i < 4; i++)
        #pragma unroll
        for (int j = 0; j < 4; j++)
          acc[i][j] = fmaf(aa[i], bb[j], acc[i][j]);
    }
    __syncthreads();
  }
  #pragma unroll
  for (int i = 0; i < 4; i++) {
    int oo = o0 + ty*4 + i;
    float bias = (oo < 512) ? cf_b1[oo] : ex_b1[oo - 512];
    __hip_bfloat16* hp = h + ((size_t)b*1536 + oo)*N_ + n0 + tx*4;
    #pragma unroll
    for (int j = 0; j < 4; j++)
      hp[j] = __float2bfloat16(fmaxf(acc[i][j] + bias, 0.f));
  }
}

// ---------------- K3: GEMM2: f = cf_w2@h1 + b (ot 0,1), p = sum_e gw_e*(ex_w2@eh_e)+bias (ot 2)
__global__ __launch_bounds__(256) void k_gemm2(
    const __hip_bfloat16* __restrict__ h,
    const float* __restrict__ cf_w2, const float* __restrict__ cf_b2,
    const float* __restrict__ ex_w2, const float* __restrict__ ex_b2,
    const float* __restrict__ gw,
    float* __restrict__ f, float* __restrict__ p)
{
  const int b  = blockIdx.z;
  const int ot = blockIdx.y;      // 0,1: f row-tiles; 2: p
  const int n0 = blockIdx.x * 64;
  const int t  = threadIdx.x;
  const int ty = t >> 4, tx = t & 15;
  __shared__ __align__(16) float Ws[16][64];
  __shared__ __align__(16) float Hs[16][64];
  float acc[4][4] = {};
  const float gw0 = gw[b*2 + 0], gw1 = gw[b*2 + 1];
  const int kdepth = (ot == 2) ? 1024 : 512;
  const int hrow0  = (ot == 2) ? 512 : 0;
  const int wr = t >> 2, wc = (t & 3) * 4;
  const int xr = t >> 4, xc = (t & 15) * 4;
  const __hip_bfloat16* hb = h + ((size_t)b*1536 + hrow0)*N_ + n0;
  for (int k0 = 0; k0 < kdepth; k0 += 16) {
    float4 wv;
    if (ot < 2) {
      wv = *(const float4*)(cf_w2 + (size_t)(ot*64 + wr)*512 + k0 + wc);
    } else {
      int e = k0 >> 9;
      float s = e ? gw1 : gw0;
      wv = *(const float4*)(ex_w2 + (size_t)e*K_*512 + (size_t)wr*512 + (k0 - (e << 9)) + wc);
      wv.x *= s; wv.y *= s; wv.z *= s; wv.w *= s;
    }
    Ws[wc+0][wr] = wv.x; Ws[wc+1][wr] = wv.y; Ws[wc+2][wr] = wv.z; Ws[wc+3][wr] = wv.w;
    const uint2 hv = *(const uint2*)(hb + (size_t)(k0 + xr)*N_ + xc);
    Hs[xr][xc+0] = __uint_as_float(hv.x << 16);
    Hs[xr][xc+1] = __uint_as_float(hv.x & 0xffff0000u);
    Hs[xr][xc+2] = __uint_as_float(hv.y << 16);
    Hs[xr][xc+3] = __uint_as_float(hv.y & 0xffff0000u);
    __syncthreads();
    #pragma unroll
    for (int kk = 0; kk < 16; kk++) {
      float4 av = *(const float4*)&Ws[kk][ty*4];
      float4 bv = *(const float4*)&Hs[kk][tx*4];
      float aa[4] = {av.x, av.y, av.z, av.w};
      float bb[4] = {bv.x, bv.y, bv.z, bv.w};
      #pragma unroll
      for (int i = 0; i < 4; i++)
        #pragma unroll
        for (int j = 0; j < 4; j++)
          acc[i][j] = fmaf(aa[i], bb[j], acc[i][j]);
    }
    __syncthreads();
  }
  if (ot < 2) {
    #pragma unroll
    for (int i = 0; i < 4; i++) {
      int d = ot*64 + ty*4 + i;
      float bias = cf_b2[d];
      float* fp = f + ((size_t)b*D_ + d)*N_ + n0 + tx*4;
      #pragma unroll
      for (int j = 0; j < 4; j++) fp[j] = acc[i][j] + bias;
    }
  } else {
    #pragma unroll
    for (int i = 0; i < 4; i++) {
      int k = ty*4 + i;
      float bias = gw0 * ex_b2[k] + gw1 * ex_b2[K_ + k];
      float* pp = p + ((size_t)b*K_ + k)*N_ + n0 + tx*4;
      #pragma unroll
      for (int j = 0; j < 4; j++) pp[j] = acc[i][j] + bias;
    }
  }
}

// ---------------- K4: Sinkhorn (log-domain, 3 iters) + exp, in place on p ----------------
__global__ __launch_bounds__(1024) void k_sinkhorn(
    float* __restrict__ p, const float* __restrict__ dust)
{
  const int b = blockIdx.x;
  const int t = threadIdx.x;
  const int wid = t >> 6, lane = t & 63;
  __shared__ float u[65];
  __shared__ float v[N_];
  const float alpha = dust[0];
  const float NORM  = -logf((float)(K_ + N_));   // -log(1088)
  const float LOGNS = logf((float)N_);
  float* pb = p + (size_t)b*K_*N_;
  v[t] = 0.f;
  __syncthreads();
  for (int it = 0; it < 3; it++) {
    // u[k] = log_mu[k] - LSE_n(Z[k,n] + v[n])
    for (int k = wid; k < 65; k += 16) {
      const bool bin = (k == 64);
      float ml = -1e30f, sl = 0.f;
      for (int n = lane; n < N_; n += 64) {
        float z = (bin ? alpha : pb[(size_t)k*N_ + n]) + v[n];
        if (z > ml) { sl = sl * __expf(ml - z) + 1.f; ml = z; }
        else sl += __expf(z - ml);
      }
      for (int off = 32; off; off >>= 1) {
        float mo = __shfl_xor(ml, off);
        float so = __shfl_xor(sl, off);
        float mn = fmaxf(ml, mo);
        sl = sl * __expf(ml - mn) + so * __expf(mo - mn);
        ml = mn;
      }
      if (lane == 0) u[k] = (bin ? (LOGNS + NORM) : NORM) - (ml + __logf(sl));
    }
    __syncthreads();
    // v[n] = log_nu - LSE_k(Z[k,n] + u[k])
    {
      float ml = -1e30f, sl = 0.f;
      for (int k = 0; k < 65; k++) {
        float z = ((k < 64) ? pb[(size_t)k*N_ + t] : alpha) + u[k];
        if (z > ml) { sl = sl * __expf(ml - z) + 1.f; ml = z; }
        else sl += __expf(z - ml);
      }
      v[t] = NORM - (ml + __logf(sl));
    }
    __syncthreads();
  }
  // P = exp(Z + u + v - norm), rows 0..63, in place
  for (int k = 0; k < 64; k++) {
    float z = pb[(size_t)k*N_ + t];
    pb[(size_t)k*N_ + t] = __expf(z + u[k] + v[t] - NORM);
  }
}

// ---------------- K5: agg = f @ P^T, per-k l2norm, assemble + final l2norm ----------------
__global__ __launch_bounds__(1024) void k_agg(
    const float* __restrict__ f, const float* __restrict__ P,
    const float* __restrict__ t_norm, float* __restrict__ out)
{
  const int b = blockIdx.x;
  const int t = threadIdx.x;
  const int wid = t >> 6, lane = t & 63;
  __shared__ float fs[128][65];
  __shared__ float Ps[64][65];
  __shared__ float invk[64];
  __shared__ float redw[16];
  __shared__ float scal[1];
  const int td = t >> 5, tk = t & 31;   // d in [td*4, td*4+4), k in [tk*2, tk*2+2)
  float acc[4][2] = {};
  const float* fb = f + (size_t)b*D_*N_;
  const float* Pb = P + (size_t)b*K_*N_;
  for (int nc = 0; nc < N_; nc += 64) {
    #pragma unroll
    for (int pp = 0; pp < 2; pp++) {
      int d = pp*64 + (t >> 4);
      int c = (t & 15) * 4;
      float4 vv = *(const float4*)(fb + (size_t)d*N_ + nc + c);
      fs[d][c+0] = vv.x; fs[d][c+1] = vv.y; fs[d][c+2] = vv.z; fs[d][c+3] = vv.w;
    }
    { int k = t >> 4; int c = (t & 15) * 4;
      float4 vv = *(const float4*)(Pb + (size_t)k*N_ + nc + c);
      Ps[k][c+0] = vv.x; Ps[k][c+1] = vv.y; Ps[k][c+2] = vv.z; Ps[k][c+3] = vv.w; }
    __syncthreads();
    #pragma unroll 4
    for (int nn = 0; nn < 64; nn++) {
      float fv[4], pv[2];
      #pragma unroll
      for (int i = 0; i < 4; i++) fv[i] = fs[td*4+i][nn];
      pv[0] = Ps[tk*2+0][nn]; pv[1] = Ps[tk*2+1][nn];
      #pragma unroll
      for (int i = 0; i < 4; i++)
        #pragma unroll
        for (int j = 0; j < 2; j++)
          acc[i][j] = fmaf(fv[i], pv[j], acc[i][j]);
    }
    __syncthreads();
  }
  // stash agg into fs[d][k]
  #pragma unroll
  for (int i = 0; i < 4; i++)
    #pragma unroll
    for (int j = 0; j < 2; j++)
      fs[td*4+i][tk*2+j] = acc[i][j];
  __syncthreads();
  // per-k sumsq partials
  { int k = t & 63, dc = t >> 6;
    float s = 0.f;
    for (int d = dc*8; d < dc*8 + 8; d++) { float w = fs[d][k]; s = fmaf(w, w, s); }
    Ps[k][dc] = s; }
  __syncthreads();
  if (t < 64) {
    float s = 0.f;
    for (int dc = 0; dc < 16; dc++) s += Ps[t][dc];
    float inv = 1.f / fmaxf(sqrtf(s), 1e-12f);
    invk[t] = inv;
    Ps[t][16] = s * inv * inv;     // contribution to total row sumsq
  }
  __syncthreads();
  float part = 0.f;
  if (t < 64)  part  = Ps[t][16];
  if (t < T_)  { float w = t_norm[b*T_ + t]; part += w*w; }
  for (int off = 32; off; off >>= 1) part += __shfl_down(part, off);
  if (lane == 0) redw[wid] = part;
  __syncthreads();
  if (t == 0) {
    float s = 0.f;
    for (int w = 0; w < 16; w++) s += redw[w];
    scal[0] = 1.f / fmaxf(sqrtf(s), 1e-12f);
  }
  __syncthreads();
  const float invt = scal[0];
  for (int idx = t; idx < OUTW; idx += 1024) {
    float vv;
    if (idx < T_) vv = t_norm[b*T_ + idx] * invt;
    else { int r = idx - T_; int d = r >> 6, k = r & 63; vv = fs[d][k] * invk[k] * invt; }
    out[(size_t)b*OUTW + idx] = vv;
  }
}

extern "C" void kernel_launch(void* const* d_in, const int* in_sizes, int n_in,
                              void* d_out, int out_size, void* d_ws, size_t ws_size,
                              hipStream_t stream)
{
  const float* x_feat = (const float*)d_in[0];
  const float* token  = (const float*)d_in[1];
  const float* cf_w1  = (const float*)d_in[2];
  const float* cf_b1  = (const float*)d_in[3];
  const float* cf_w2  = (const float*)d_in[4];
  const float* cf_b2  = (const float*)d_in[5];
  const float* tf_w1  = (const float*)d_in[6];
  const float* tf_b1  = (const float*)d_in[7];
  const float* tf_w2  = (const float*)d_in[8];
  const float* tf_b2  = (const float*)d_in[9];
  const float* ex_w1  = (const float*)d_in[10];
  const float* ex_b1  = (const float*)d_in[11];
  const float* ex_w2  = (const float*)d_in[12];
  const float* ex_b2  = (const float*)d_in[13];
  const float* g_w1   = (const float*)d_in[14];
  const float* g_b1   = (const float*)d_in[15];
  const float* g_w2   = (const float*)d_in[16];
  const float* g_b2   = (const float*)d_in[17];
  const float* dust   = (const float*)d_in[18];
  float* out = (float*)d_out;

  char* ws = (char*)d_ws;
  float* t_norm       = (float*)(ws + 0);                      // 16 KB
  float* gw           = (float*)(ws + 16384);                  // 128 B
  __hip_bfloat16* h   = (__hip_bfloat16*)(ws + 32768);         // 16*1536*1024*2 = 50331648
  float* f            = (float*)(ws + 32768 + 50331648);       // 16*128*1024*4 = 8388608
  float* p            = (float*)(ws + 32768 + 50331648 + 8388608); // 16*64*1024*4 = 4194304

  k_token<<<dim3(16), dim3(256), 0, stream>>>(token, tf_w1, tf_b1, tf_w2, tf_b2,
                                              g_w1, g_b1, g_w2, g_b2, t_norm, gw);
  k_gemm1<<<dim3(16, 24, 16), dim3(256), 0, stream>>>(x_feat, cf_w1, cf_b1, ex_w1, ex_b1, h);
  k_gemm2<<<dim3(16, 3, 16), dim3(256), 0, stream>>>(h, cf_w2, cf_b2, ex_w2, ex_b2, gw, f, p);
  k_sinkhorn<<<dim3(16), dim3(1024), 0, stream>>>(p, dust);
  k_agg<<<dim3(16), dim3(1024), 0, stream>>>(f, p, t_norm, out);
}

// Round 5
// 611.173 us; speedup vs baseline: 4.8854x; 4.8854x over previous
//
#include <hip/hip_runtime.h>
#include <hip/hip_bf16.h>
#include <math.h>

#define B_  16
#define C_  1536
#define N_  1024
#define K_  64
#define D_  128
#define T_  256
#define OUTW (T_ + D_*K_)   // 8448

typedef __attribute__((ext_vector_type(8))) short short8_t;
typedef __attribute__((ext_vector_type(4))) float f32x4;

__device__ __forceinline__ ushort f2bf(float f){
  union { float f; uint u; } x; x.f = f;
  return (ushort)((x.u + 0x7fffu + ((x.u >> 16) & 1u)) >> 16);
}
__device__ __forceinline__ float bf2f(ushort u){ return __uint_as_float(((uint)u) << 16); }

__device__ __forceinline__ void gload16(const ushort* g, ushort* l){
  __builtin_amdgcn_global_load_lds((const __attribute__((address_space(1))) void*)g,
                                   (__attribute__((address_space(3))) void*)l, 16, 0, 0);
}

// ---------------- prep: weights fp32 -> bf16 (stacked 1536x1536) ----------------
__global__ __launch_bounds__(256) void k_prep_w(
    const float* __restrict__ cf_w1, const float* __restrict__ ex_w1,
    ushort* __restrict__ Wbf)
{
  size_t i = ((size_t)blockIdx.x*256 + threadIdx.x) * 8;
  const float* src = (i < (size_t)512*C_) ? (cf_w1 + i) : (ex_w1 + (i - (size_t)512*C_));
  float4 a = *(const float4*)(src);
  float4 b = *(const float4*)(src + 4);
  uint4 ov;
  ov.x = (uint)f2bf(a.x) | ((uint)f2bf(a.y) << 16);
  ov.y = (uint)f2bf(a.z) | ((uint)f2bf(a.w) << 16);
  ov.z = (uint)f2bf(b.x) | ((uint)f2bf(b.y) << 16);
  ov.w = (uint)f2bf(b.z) | ((uint)f2bf(b.w) << 16);
  *(uint4*)(Wbf + i) = ov;
}

// ---------------- prep: x [b][c][n] fp32 -> xT [b-b0][n][c] bf16 ----------------
__global__ __launch_bounds__(256) void k_prep_x(
    const float* __restrict__ x, ushort* __restrict__ xT, int b0)
{
  const int bx = blockIdx.x;   // n tile (16)
  const int by = blockIdx.y;   // c tile (24)
  const int bz = blockIdx.z;   // local batch (8)
  const int t  = threadIdx.x;
  __shared__ float Ls[64][65];
  const float* xb = x + (size_t)(bz + b0)*C_*N_ + (size_t)by*64*N_ + bx*64;
  const int r  = t >> 4;            // 0..15
  const int cq = (t & 15) * 4;      // n col quad
  #pragma unroll
  for (int p = 0; p < 4; p++) {
    float4 v = *(const float4*)(xb + (size_t)(r + p*16)*N_ + cq);
    Ls[r + p*16][cq+0] = v.x; Ls[r + p*16][cq+1] = v.y;
    Ls[r + p*16][cq+2] = v.z; Ls[r + p*16][cq+3] = v.w;
  }
  __syncthreads();
  ushort* xTb = xT + ((size_t)bz*N_ + (size_t)bx*64)*C_ + by*64;
  const int rn = t >> 3;            // 0..31
  const int cc = (t & 7) * 8;       // c offset
  #pragma unroll
  for (int p = 0; p < 2; p++) {
    int n = rn + p*32;
    uint4 ov;
    ov.x = (uint)f2bf(Ls[cc+0][n]) | ((uint)f2bf(Ls[cc+1][n]) << 16);
    ov.y = (uint)f2bf(Ls[cc+2][n]) | ((uint)f2bf(Ls[cc+3][n]) << 16);
    ov.z = (uint)f2bf(Ls[cc+4][n]) | ((uint)f2bf(Ls[cc+5][n]) << 16);
    ov.w = (uint)f2bf(Ls[cc+6][n]) | ((uint)f2bf(Ls[cc+7][n]) << 16);
    *(uint4*)(xTb + (size_t)n*C_ + cc) = ov;
  }
}

// ---------------- token path A: th1[b][512], gh[b][128] ----------------
__global__ __launch_bounds__(256) void k_token_a(
    const float* __restrict__ token,
    const float* __restrict__ tf_w1, const float* __restrict__ tf_b1,
    const float* __restrict__ g_w1, const float* __restrict__ g_b1,
    float* __restrict__ th1, float* __restrict__ gh)
{
  const int b = blockIdx.y;
  const int o = blockIdx.x*4 + (threadIdx.x >> 6);
  const int lane = threadIdx.x & 63;
  const float* w; float bias; float* dst;
  if (o < 512) { w = tf_w1 + (size_t)o*C_; bias = tf_b1[o]; dst = th1 + b*512 + o; }
  else { int oo = o - 512; w = g_w1 + (size_t)oo*C_; bias = g_b1[oo]; dst = gh + b*128 + oo; }
  const float* tok = token + (size_t)b*C_;
  float s = 0.f;
  for (int c = lane; c < C_; c += 64) s = fmaf(tok[c], w[c], s);
  for (int off = 32; off; off >>= 1) s += __shfl_down(s, off);
  if (lane == 0) *dst = fmaxf(s + bias, 0.f);
}

// ---------------- token path B: tt[b][256] raw, gate softmax -> gw ----------------
__global__ __launch_bounds__(256) void k_token_b(
    const float* __restrict__ th1, const float* __restrict__ gh,
    const float* __restrict__ tf_w2, const float* __restrict__ tf_b2,
    const float* __restrict__ g_w2, const float* __restrict__ g_b2,
    float* __restrict__ tt, float* __restrict__ gw)
{
  const int b = blockIdx.y;
  const int wid = threadIdx.x >> 6, lane = threadIdx.x & 63;
  if (blockIdx.x < 64) {
    const int o = blockIdx.x*4 + wid;
    const float* w = tf_w2 + (size_t)o*512;
    const float* h = th1 + b*512;
    float s = 0.f;
    for (int c = lane; c < 512; c += 64) s = fmaf(h[c], w[c], s);
    for (int off = 32; off; off >>= 1) s += __shfl_down(s, off);
    if (lane == 0) tt[b*T_ + o] = s + tf_b2[o];
  } else {
    __shared__ float gl[2];
    if (wid < 2) {
      const float* w = g_w2 + wid*128;
      const float* h = gh + b*128;
      float s = 0.f;
      for (int c = lane; c < 128; c += 64) s = fmaf(h[c], w[c], s);
      for (int off = 32; off; off >>= 1) s += __shfl_down(s, off);
      if (lane == 0) gl[wid] = s + g_b2[wid];
    }
    __syncthreads();
    if (threadIdx.x == 0) {
      float m = fmaxf(gl[0], gl[1]);
      float e0 = __expf(gl[0]-m), e1 = __expf(gl[1]-m);
      float inv = 1.f / (e0 + e1);
      gw[b*2+0] = e0*inv; gw[b*2+1] = e1*inv;
    }
  }
}

// ---------------- GEMM1 (bf16 MFMA): hT[b][n][o] = relu(W@x + bias) ----------------
// 128x128 tile, BK=64, 4 waves (2x2), mfma_f32_16x16x32_bf16
__global__ __launch_bounds__(256) void k_gemm1(
    const ushort* __restrict__ Wbf, const ushort* __restrict__ xT,
    const float* __restrict__ cf_b1, const float* __restrict__ ex_b1,
    ushort* __restrict__ hT, int b0)
{
  const int bx = blockIdx.x;       // n tile (8)
  const int by = blockIdx.y;       // o tile (12)
  const int bz = blockIdx.z;       // local batch (8)
  const int t = threadIdx.x;
  const int wid = t >> 6, lane = t & 63;
  const int wr = wid >> 1, wc = wid & 1;
  __shared__ ushort Abuf[128*64];
  __shared__ ushort Bbuf[128*64];
  f32x4 acc[4][4];
  const f32x4 z4 = {0.f, 0.f, 0.f, 0.f};
  #pragma unroll
  for (int i = 0; i < 4; i++)
    #pragma unroll
    for (int j = 0; j < 4; j++) acc[i][j] = z4;

  // staging: linear LDS dest; swizzled global source (slot s = ps ^ (row&7))
  const ushort* gA[4]; const ushort* gB[4];
  ushort* lA[4]; ushort* lB[4];
  #pragma unroll
  for (int j = 0; j < 4; j++) {
    int idx = j*256 + t;
    int row = idx >> 3, ps = idx & 7;
    int s = ps ^ (row & 7);
    gA[j] = Wbf + (size_t)(by*128 + row)*C_ + s*8;
    gB[j] = xT + ((size_t)bz*N_ + bx*128 + row)*C_ + s*8;
    lA[j] = &Abuf[(j*4 + wid)*512];
    lB[j] = &Bbuf[(j*4 + wid)*512];
  }

  for (int k0 = 0; k0 < C_; k0 += 64) {
    #pragma unroll
    for (int j = 0; j < 4; j++) {
      gload16(gA[j] + k0, lA[j]);
      gload16(gB[j] + k0, lB[j]);
    }
    __syncthreads();
    #pragma unroll
    for (int ks = 0; ks < 2; ks++) {
      short8_t a[4], bb[4];
      const int l15 = lane & 15, lg = lane >> 4;
      #pragma unroll
      for (int i = 0; i < 4; i++) {
        int row = wr*64 + i*16 + l15;
        int slot = ks*4 + lg;
        a[i] = *(const short8_t*)&Abuf[row*64 + ((slot ^ (row & 7)) * 8)];
      }
      #pragma unroll
      for (int j = 0; j < 4; j++) {
        int row = wc*64 + j*16 + l15;
        int slot = ks*4 + lg;
        bb[j] = *(const short8_t*)&Bbuf[row*64 + ((slot ^ (row & 7)) * 8)];
      }
      #pragma unroll
      for (int i = 0; i < 4; i++)
        #pragma unroll
        for (int j = 0; j < 4; j++)
          acc[i][j] = __builtin_amdgcn_mfma_f32_16x16x32_bf16(a[i], bb[j], acc[i][j], 0, 0, 0);
    }
    __syncthreads();
  }
  // epilogue: bias + relu + bf16, packed 8B stores into hT[b][n][o]
  const int lr = lane >> 4, lc = lane & 15;
  #pragma unroll
  for (int i = 0; i < 4; i++) {
    int o4 = by*128 + wr*64 + i*16 + lr*4;
    float4 bi = (o4 < 512) ? *(const float4*)(cf_b1 + o4)
                           : *(const float4*)(ex_b1 + o4 - 512);
    #pragma unroll
    for (int j = 0; j < 4; j++) {
      int n = bx*128 + wc*64 + j*16 + lc;
      f32x4 v = acc[i][j];
      ushort4 pk;
      pk.x = f2bf(fmaxf(v[0] + bi.x, 0.f));
      pk.y = f2bf(fmaxf(v[1] + bi.y, 0.f));
      pk.z = f2bf(fmaxf(v[2] + bi.z, 0.f));
      pk.w = f2bf(fmaxf(v[3] + bi.w, 0.f));
      *(ushort4*)(hT + ((size_t)(b0 + bz)*N_ + n)*1536 + o4) = pk;
    }
  }
}

// ---------------- GEMM2: f = cf_w2@h1 + b (ot 0,1), p = sum_e gw_e*(ex_w2@eh_e)+bias (ot 2)
// reads hT[b][n][o] (o = k-dim, contiguous)
__global__ __launch_bounds__(256) void k_gemm2(
    const ushort* __restrict__ hT,
    const float* __restrict__ cf_w2, const float* __restrict__ cf_b2,
    const float* __restrict__ ex_w2, const float* __restrict__ ex_b2,
    const float* __restrict__ gw,
    float* __restrict__ f, float* __restrict__ p)
{
  const int b  = blockIdx.z;
  const int ot = blockIdx.y;      // 0,1: f row-tiles; 2: p
  const int n0 = blockIdx.x * 64;
  const int t  = threadIdx.x;
  const int ty = t >> 4, tx = t & 15;
  __shared__ __align__(16) float Ws[16][64];
  __shared__ __align__(16) float Hs[16][64];
  float acc[4][4] = {};
  const float gw0 = gw[b*2 + 0], gw1 = gw[b*2 + 1];
  const int kdepth = (ot == 2) ? 1024 : 512;
  const int hrow0  = (ot == 2) ? 512 : 0;
  const int wr = t >> 2, wc4 = (t & 3) * 4;
  const int hn = t >> 2, ho = (t & 3) * 4;
  const ushort* hTb = hT + ((size_t)b*N_ + n0)*1536 + hrow0;
  for (int k0 = 0; k0 < kdepth; k0 += 16) {
    float4 wv;
    if (ot < 2) {
      wv = *(const float4*)(cf_w2 + (size_t)(ot*64 + wr)*512 + k0 + wc4);
    } else {
      int e = k0 >> 9;
      float s = e ? gw1 : gw0;
      wv = *(const float4*)(ex_w2 + (size_t)e*K_*512 + (size_t)wr*512 + (k0 - (e << 9)) + wc4);
      wv.x *= s; wv.y *= s; wv.z *= s; wv.w *= s;
    }
    Ws[wc4+0][wr] = wv.x; Ws[wc4+1][wr] = wv.y; Ws[wc4+2][wr] = wv.z; Ws[wc4+3][wr] = wv.w;
    const ushort4 hv = *(const ushort4*)(hTb + (size_t)hn*1536 + k0 + ho);
    Hs[ho+0][hn] = bf2f(hv.x);
    Hs[ho+1][hn] = bf2f(hv.y);
    Hs[ho+2][hn] = bf2f(hv.z);
    Hs[ho+3][hn] = bf2f(hv.w);
    __syncthreads();
    #pragma unroll
    for (int kk = 0; kk < 16; kk++) {
      float4 av = *(const float4*)&Ws[kk][ty*4];
      float4 bv = *(const float4*)&Hs[kk][tx*4];
      float aa[4] = {av.x, av.y, av.z, av.w};
      float bb[4] = {bv.x, bv.y, bv.z, bv.w};
      #pragma unroll
      for (int i = 0; i < 4; i++)
        #pragma unroll
        for (int j = 0; j < 4; j++)
          acc[i][j] = fmaf(aa[i], bb[j], acc[i][j]);
    }
    __syncthreads();
  }
  if (ot < 2) {
    #pragma unroll
    for (int i = 0; i < 4; i++) {
      int d = ot*64 + ty*4 + i;
      float bias = cf_b2[d];
      float* fp = f + ((size_t)b*D_ + d)*N_ + n0 + tx*4;
      #pragma unroll
      for (int j = 0; j < 4; j++) fp[j] = acc[i][j] + bias;
    }
  } else {
    #pragma unroll
    for (int i = 0; i < 4; i++) {
      int k = ty*4 + i;
      float bias = gw0 * ex_b2[k] + gw1 * ex_b2[K_ + k];
      float* pp = p + ((size_t)b*K_ + k)*N_ + n0 + tx*4;
      #pragma unroll
      for (int j = 0; j < 4; j++) pp[j] = acc[i][j] + bias;
    }
  }
}

// ---------------- Sinkhorn (log-domain, 3 iters) + exp, in place on p ----------------
__global__ __launch_bounds__(1024) void k_sinkhorn(
    float* __restrict__ p, const float* __restrict__ dust)
{
  const int b = blockIdx.x;
  const int t = threadIdx.x;
  const int wid = t >> 6, lane = t & 63;
  __shared__ float u[65];
  __shared__ float v[N_];
  const float alpha = dust[0];
  const float NORM  = -logf((float)(K_ + N_));
  const float LOGNS = logf((float)N_);
  float* pb = p + (size_t)b*K_*N_;
  v[t] = 0.f;
  __syncthreads();
  for (int it = 0; it < 3; it++) {
    for (int k = wid; k < 65; k += 16) {
      const bool bin = (k == 64);
      float ml = -1e30f, sl = 0.f;
      for (int n = lane; n < N_; n += 64) {
        float z = (bin ? alpha : pb[(size_t)k*N_ + n]) + v[n];
        if (z > ml) { sl = sl * __expf(ml - z) + 1.f; ml = z; }
        else sl += __expf(z - ml);
      }
      for (int off = 32; off; off >>= 1) {
        float mo = __shfl_xor(ml, off);
        float so = __shfl_xor(sl, off);
        float mn = fmaxf(ml, mo);
        sl = sl * __expf(ml - mn) + so * __expf(mo - mn);
        ml = mn;
      }
      if (lane == 0) u[k] = (bin ? (LOGNS + NORM) : NORM) - (ml + __logf(sl));
    }
    __syncthreads();
    {
      float ml = -1e30f, sl = 0.f;
      for (int k = 0; k < 65; k++) {
        float z = ((k < 64) ? pb[(size_t)k*N_ + t] : alpha) + u[k];
        if (z > ml) { sl = sl * __expf(ml - z) + 1.f; ml = z; }
        else sl += __expf(z - ml);
      }
      v[t] = NORM - (ml + __logf(sl));
    }
    __syncthreads();
  }
  for (int k = 0; k < 64; k++) {
    float z = pb[(size_t)k*N_ + t];
    pb[(size_t)k*N_ + t] = __expf(z + u[k] + v[t] - NORM);
  }
}

// ---------------- agg = f @ P^T, norms, assemble ----------------
__global__ __launch_bounds__(1024) void k_agg(
    const float* __restrict__ f, const float* __restrict__ P,
    const float* __restrict__ tt_g, float* __restrict__ out)
{
  const int b = blockIdx.x;
  const int t = threadIdx.x;
  const int wid = t >> 6, lane = t & 63;
  __shared__ float fs[128][65];
  __shared__ float Ps[64][65];
  __shared__ float invk[64];
  __shared__ float redw[16];
  __shared__ float redw2[16];
  __shared__ float tts[256];
  __shared__ float scal[2];
  if (t < 256) tts[t] = tt_g[b*T_ + t];
  const int td = t >> 5, tk = t & 31;
  float acc[4][2] = {};
  const float* fb = f + (size_t)b*D_*N_;
  const float* Pb = P + (size_t)b*K_*N_;
  for (int nc = 0; nc < N_; nc += 64) {
    #pragma unroll
    for (int pp = 0; pp < 2; pp++) {
      int d = pp*64 + (t >> 4);
      int c = (t & 15) * 4;
      float4 vv = *(const float4*)(fb + (size_t)d*N_ + nc + c);
      fs[d][c+0] = vv.x; fs[d][c+1] = vv.y; fs[d][c+2] = vv.z; fs[d][c+3] = vv.w;
    }
    { int k = t >> 4; int c = (t & 15) * 4;
      float4 vv = *(const float4*)(Pb + (size_t)k*N_ + nc + c);
      Ps[k][c+0] = vv.x; Ps[k][c+1] = vv.y; Ps[k][c+2] = vv.z; Ps[k][c+3] = vv.w; }
    __syncthreads();
    #pragma unroll 4
    for (int nn = 0; nn < 64; nn++) {
      float fv[4], pv[2];
      #pragma unroll
      for (int i = 0; i < 4; i++) fv[i] = fs[td*4+i][nn];
      pv[0] = Ps[tk*2+0][nn]; pv[1] = Ps[tk*2+1][nn];
      #pragma unroll
      for (int i = 0; i < 4; i++)
        #pragma unroll
        for (int j = 0; j < 2; j++)
          acc[i][j] = fmaf(fv[i], pv[j], acc[i][j]);
    }
    __syncthreads();
  }
  #pragma unroll
  for (int i = 0; i < 4; i++)
    #pragma unroll
    for (int j = 0; j < 2; j++)
      fs[td*4+i][tk*2+j] = acc[i][j];
  __syncthreads();
  { int k = t & 63, dc = t >> 6;
    float s = 0.f;
    for (int d = dc*8; d < dc*8 + 8; d++) { float w = fs[d][k]; s = fmaf(w, w, s); }
    Ps[k][dc] = s; }
  __syncthreads();
  if (t < 64) {
    float s = 0.f;
    for (int dc = 0; dc < 16; dc++) s += Ps[t][dc];
    float inv = 1.f / fmaxf(sqrtf(s), 1e-12f);
    invk[t] = inv;
    Ps[t][16] = s * inv * inv;
  }
  __syncthreads();
  float p1 = 0.f, p2 = 0.f;
  if (t < 64)  p2 = Ps[t][16];
  if (t < T_)  { float w = tts[t]; p1 = w*w; }
  for (int off = 32; off; off >>= 1) { p1 += __shfl_down(p1, off); p2 += __shfl_down(p2, off); }
  if (lane == 0) { redw[wid] = p1; redw2[wid] = p2; }
  __syncthreads();
  if (t == 0) {
    float s1 = 0.f, s2 = 0.f;
    for (int w = 0; w < 16; w++) { s1 += redw[w]; s2 += redw2[w]; }
    float invT = 1.f / fmaxf(sqrtf(s1), 1e-12f);
    float tot  = s1*invT*invT + s2;
    float invG = 1.f / fmaxf(sqrtf(tot), 1e-12f);
    scal[0] = invG;
    scal[1] = invT * invG;
  }
  __syncthreads();
  const float invG = scal[0], invTG = scal[1];
  for (int idx = t; idx < OUTW; idx += 1024) {
    float vv;
    if (idx < T_) vv = tts[idx] * invTG;
    else { int r = idx - T_; int d = r >> 6, k = r & 63; vv = fs[d][k] * invk[k] * invG; }
    out[(size_t)b*OUTW + idx] = vv;
  }
}

extern "C" void kernel_launch(void* const* d_in, const int* in_sizes, int n_in,
                              void* d_out, int out_size, void* d_ws, size_t ws_size,
                              hipStream_t stream)
{
  const float* x_feat = (const float*)d_in[0];
  const float* token  = (const float*)d_in[1];
  const float* cf_w1  = (const float*)d_in[2];
  const float* cf_b1  = (const float*)d_in[3];
  const float* cf_w2  = (const float*)d_in[4];
  const float* cf_b2  = (const float*)d_in[5];
  const float* tf_w1  = (const float*)d_in[6];
  const float* tf_b1  = (const float*)d_in[7];
  const float* tf_w2  = (const float*)d_in[8];
  const float* tf_b2  = (const float*)d_in[9];
  const float* ex_w1  = (const float*)d_in[10];
  const float* ex_b1  = (const float*)d_in[11];
  const float* ex_w2  = (const float*)d_in[12];
  const float* ex_b2  = (const float*)d_in[13];
  const float* g_w1   = (const float*)d_in[14];
  const float* g_b1   = (const float*)d_in[15];
  const float* g_w2   = (const float*)d_in[16];
  const float* g_b2   = (const float*)d_in[17];
  const float* dust   = (const float*)d_in[18];
  float* out = (float*)d_out;

  char* ws = (char*)d_ws;
  float*  tt   = (float*)(ws + 0);            // 16 KB
  float*  gw   = (float*)(ws + 65536);        // 128 B
  float*  th1  = (float*)(ws + 131072);       // 32 KB
  float*  gh   = (float*)(ws + 262144);       // 8 KB
  ushort* Wbf  = (ushort*)(ws + 524288);      // 4.5 MB  (ends 5,242,880)
  ushort* xT   = (ushort*)(ws + 8388608);     // 24 MB (8 batches)  (ends 33,554,432)
  ushort* hT   = (ushort*)(ws + 33554432);    // 48 MB  (ends 83,886,080)
  float*  f    = (float*)(ws + 8388608);      // alias over xT (dead by then): 8 MB
  float*  p    = (float*)(ws + 8388608 + 8388608); // 4 MB, still within xT region

  k_prep_w<<<dim3(1152), dim3(256), 0, stream>>>(cf_w1, ex_w1, Wbf);
  k_token_a<<<dim3(160, 16), dim3(256), 0, stream>>>(token, tf_w1, tf_b1, g_w1, g_b1, th1, gh);
  k_token_b<<<dim3(65, 16), dim3(256), 0, stream>>>(th1, gh, tf_w2, tf_b2, g_w2, g_b2, tt, gw);
  for (int ph = 0; ph < 2; ph++) {
    k_prep_x<<<dim3(16, 24, 8), dim3(256), 0, stream>>>(x_feat, xT, ph*8);
    k_gemm1<<<dim3(8, 12, 8), dim3(256), 0, stream>>>(Wbf, xT, cf_b1, ex_b1, hT, ph*8);
  }
  k_gemm2<<<dim3(16, 3, 16), dim3(256), 0, stream>>>(hT, cf_w2, cf_b2, ex_w2, ex_b2, gw, f, p);
  k_sinkhorn<<<dim3(16), dim3(1024), 0, stream>>>(p, dust);
  k_agg<<<dim3(16), dim3(1024), 0, stream>>>(f, p, tt, out);
}

// Round 7
// 475.688 us; speedup vs baseline: 6.2768x; 1.2848x over previous
//
#include <hip/hip_runtime.h>
#include <hip/hip_bf16.h>
#include <math.h>

#define B_  16
#define C_  1536
#define N_  1024
#define K_  64
#define D_  128
#define T_  256
#define OUTW (T_ + D_*K_)   // 8448

typedef __attribute__((ext_vector_type(8))) short short8_t;
typedef __attribute__((ext_vector_type(4))) float f32x4;

__device__ __forceinline__ ushort f2bf(float f){
  union { float f; uint u; } x; x.f = f;
  return (ushort)((x.u + 0x7fffu + ((x.u >> 16) & 1u)) >> 16);
}

__device__ __forceinline__ void gload16(const ushort* g, ushort* l){
  __builtin_amdgcn_global_load_lds((const __attribute__((address_space(1))) void*)g,
                                   (__attribute__((address_space(3))) void*)l, 16, 0, 0);
}

// ---------------- prep: W1 weights fp32 -> bf16 (stacked 1536x1536) ----------------
__global__ __launch_bounds__(256) void k_prep_w(
    const float* __restrict__ cf_w1, const float* __restrict__ ex_w1,
    ushort* __restrict__ Wbf)
{
  size_t i = ((size_t)blockIdx.x*256 + threadIdx.x) * 8;
  const float* src = (i < (size_t)512*C_) ? (cf_w1 + i) : (ex_w1 + (i - (size_t)512*C_));
  float4 a = *(const float4*)(src);
  float4 b = *(const float4*)(src + 4);
  uint4 ov;
  ov.x = (uint)f2bf(a.x) | ((uint)f2bf(a.y) << 16);
  ov.y = (uint)f2bf(a.z) | ((uint)f2bf(a.w) << 16);
  ov.z = (uint)f2bf(b.x) | ((uint)f2bf(b.y) << 16);
  ov.w = (uint)f2bf(b.z) | ((uint)f2bf(b.w) << 16);
  *(uint4*)(Wbf + i) = ov;
}

// ---------------- prep: W2 weights fp32 -> bf16 ([0..127]=cf_w2, [128..255]=ex_w2) ----
__global__ __launch_bounds__(256) void k_prep_w2(
    const float* __restrict__ cf_w2, const float* __restrict__ ex_w2,
    ushort* __restrict__ W2bf)
{
  size_t i = ((size_t)blockIdx.x*256 + threadIdx.x) * 8;   // 64 blocks -> 131072 elems
  const float* src = (i < (size_t)65536) ? (cf_w2 + i) : (ex_w2 + (i - 65536));
  float4 a = *(const float4*)(src);
  float4 b = *(const float4*)(src + 4);
  uint4 ov;
  ov.x = (uint)f2bf(a.x) | ((uint)f2bf(a.y) << 16);
  ov.y = (uint)f2bf(a.z) | ((uint)f2bf(a.w) << 16);
  ov.z = (uint)f2bf(b.x) | ((uint)f2bf(b.y) << 16);
  ov.w = (uint)f2bf(b.z) | ((uint)f2bf(b.w) << 16);
  *(uint4*)(W2bf + i) = ov;
}

// ---------------- prep: x [b][c][n] fp32 -> xT [b-b0][n][c] bf16 ----------------
__global__ __launch_bounds__(256) void k_prep_x(
    const float* __restrict__ x, ushort* __restrict__ xT, int b0)
{
  const int bx = blockIdx.x;   // n tile (16)
  const int by = blockIdx.y;   // c tile (24)
  const int bz = blockIdx.z;   // local batch (8)
  const int t  = threadIdx.x;
  __shared__ float Ls[64][65];
  const float* xb = x + (size_t)(bz + b0)*C_*N_ + (size_t)by*64*N_ + bx*64;
  const int r  = t >> 4;
  const int cq = (t & 15) * 4;
  #pragma unroll
  for (int p = 0; p < 4; p++) {
    float4 v = *(const float4*)(xb + (size_t)(r + p*16)*N_ + cq);
    Ls[r + p*16][cq+0] = v.x; Ls[r + p*16][cq+1] = v.y;
    Ls[r + p*16][cq+2] = v.z; Ls[r + p*16][cq+3] = v.w;
  }
  __syncthreads();
  ushort* xTb = xT + ((size_t)bz*N_ + (size_t)bx*64)*C_ + by*64;
  const int rn = t >> 3;
  const int cc = (t & 7) * 8;
  #pragma unroll
  for (int p = 0; p < 2; p++) {
    int n = rn + p*32;
    uint4 ov;
    ov.x = (uint)f2bf(Ls[cc+0][n]) | ((uint)f2bf(Ls[cc+1][n]) << 16);
    ov.y = (uint)f2bf(Ls[cc+2][n]) | ((uint)f2bf(Ls[cc+3][n]) << 16);
    ov.z = (uint)f2bf(Ls[cc+4][n]) | ((uint)f2bf(Ls[cc+5][n]) << 16);
    ov.w = (uint)f2bf(Ls[cc+6][n]) | ((uint)f2bf(Ls[cc+7][n]) << 16);
    *(uint4*)(xTb + (size_t)n*C_ + cc) = ov;
  }
}

// ---------------- token path A: th1[b][512], gh[b][128] ----------------
__global__ __launch_bounds__(256) void k_token_a(
    const float* __restrict__ token,
    const float* __restrict__ tf_w1, const float* __restrict__ tf_b1,
    const float* __restrict__ g_w1, const float* __restrict__ g_b1,
    float* __restrict__ th1, float* __restrict__ gh)
{
  const int b = blockIdx.y;
  const int o = blockIdx.x*4 + (threadIdx.x >> 6);
  const int lane = threadIdx.x & 63;
  const float* w; float bias; float* dst;
  if (o < 512) { w = tf_w1 + (size_t)o*C_; bias = tf_b1[o]; dst = th1 + b*512 + o; }
  else { int oo = o - 512; w = g_w1 + (size_t)oo*C_; bias = g_b1[oo]; dst = gh + b*128 + oo; }
  const float* tok = token + (size_t)b*C_;
  float s = 0.f;
  for (int c = lane; c < C_; c += 64) s = fmaf(tok[c], w[c], s);
  for (int off = 32; off; off >>= 1) s += __shfl_down(s, off);
  if (lane == 0) *dst = fmaxf(s + bias, 0.f);
}

// ---------------- token path B: tt[b][256] raw, gate softmax -> gw ----------------
__global__ __launch_bounds__(256) void k_token_b(
    const float* __restrict__ th1, const float* __restrict__ gh,
    const float* __restrict__ tf_w2, const float* __restrict__ tf_b2,
    const float* __restrict__ g_w2, const float* __restrict__ g_b2,
    float* __restrict__ tt, float* __restrict__ gw)
{
  const int b = blockIdx.y;
  const int wid = threadIdx.x >> 6, lane = threadIdx.x & 63;
  if (blockIdx.x < 64) {
    const int o = blockIdx.x*4 + wid;
    const float* w = tf_w2 + (size_t)o*512;
    const float* h = th1 + b*512;
    float s = 0.f;
    for (int c = lane; c < 512; c += 64) s = fmaf(h[c], w[c], s);
    for (int off = 32; off; off >>= 1) s += __shfl_down(s, off);
    if (lane == 0) tt[b*T_ + o] = s + tf_b2[o];
  } else {
    __shared__ float gl[2];
    if (wid < 2) {
      const float* w = g_w2 + wid*128;
      const float* h = gh + b*128;
      float s = 0.f;
      for (int c = lane; c < 128; c += 64) s = fmaf(h[c], w[c], s);
      for (int off = 32; off; off >>= 1) s += __shfl_down(s, off);
      if (lane == 0) gl[wid] = s + g_b2[wid];
    }
    __syncthreads();
    if (threadIdx.x == 0) {
      float m = fmaxf(gl[0], gl[1]);
      float e0 = __expf(gl[0]-m), e1 = __expf(gl[1]-m);
      float inv = 1.f / (e0 + e1);
      gw[b*2+0] = e0*inv; gw[b*2+1] = e1*inv;
    }
  }
}

// ---------------- GEMM1 (bf16 MFMA): hT[b][n][o] = relu(W@x + bias) ----------------
__global__ __launch_bounds__(256) void k_gemm1(
    const ushort* __restrict__ Wbf, const ushort* __restrict__ xT,
    const float* __restrict__ cf_b1, const float* __restrict__ ex_b1,
    ushort* __restrict__ hT, int b0)
{
  const int bx = blockIdx.x;       // n tile (8)
  const int by = blockIdx.y;       // o tile (12)
  const int bz = blockIdx.z;       // local batch (8)
  const int t = threadIdx.x;
  const int wid = t >> 6, lane = t & 63;
  const int wr = wid >> 1, wc = wid & 1;
  __shared__ ushort Abuf[128*64];
  __shared__ ushort Bbuf[128*64];
  f32x4 acc[4][4];
  const f32x4 z4 = {0.f, 0.f, 0.f, 0.f};
  #pragma unroll
  for (int i = 0; i < 4; i++)
    #pragma unroll
    for (int j = 0; j < 4; j++) acc[i][j] = z4;

  const ushort* gA[4]; const ushort* gB[4];
  ushort* lA[4]; ushort* lB[4];
  #pragma unroll
  for (int j = 0; j < 4; j++) {
    int idx = j*256 + t;
    int row = idx >> 3, ps = idx & 7;
    int s = ps ^ (row & 7);
    gA[j] = Wbf + (size_t)(by*128 + row)*C_ + s*8;
    gB[j] = xT + ((size_t)bz*N_ + bx*128 + row)*C_ + s*8;
    lA[j] = &Abuf[(j*4 + wid)*512];
    lB[j] = &Bbuf[(j*4 + wid)*512];
  }

  for (int k0 = 0; k0 < C_; k0 += 64) {
    #pragma unroll
    for (int j = 0; j < 4; j++) {
      gload16(gA[j] + k0, lA[j]);
      gload16(gB[j] + k0, lB[j]);
    }
    __syncthreads();
    #pragma unroll
    for (int ks = 0; ks < 2; ks++) {
      short8_t a[4], bb[4];
      const int l15 = lane & 15, lg = lane >> 4;
      #pragma unroll
      for (int i = 0; i < 4; i++) {
        int row = wr*64 + i*16 + l15;
        int slot = ks*4 + lg;
        a[i] = *(const short8_t*)&Abuf[row*64 + ((slot ^ (row & 7)) * 8)];
      }
      #pragma unroll
      for (int j = 0; j < 4; j++) {
        int row = wc*64 + j*16 + l15;
        int slot = ks*4 + lg;
        bb[j] = *(const short8_t*)&Bbuf[row*64 + ((slot ^ (row & 7)) * 8)];
      }
      #pragma unroll
      for (int i = 0; i < 4; i++)
        #pragma unroll
        for (int j = 0; j < 4; j++)
          acc[i][j] = __builtin_amdgcn_mfma_f32_16x16x32_bf16(a[i], bb[j], acc[i][j], 0, 0, 0);
    }
    __syncthreads();
  }
  const int lr = lane >> 4, lc = lane & 15;
  #pragma unroll
  for (int i = 0; i < 4; i++) {
    int o4 = by*128 + wr*64 + i*16 + lr*4;
    float4 bi = (o4 < 512) ? *(const float4*)(cf_b1 + o4)
                           : *(const float4*)(ex_b1 + o4 - 512);
    #pragma unroll
    for (int j = 0; j < 4; j++) {
      int n = bx*128 + wc*64 + j*16 + lc;
      f32x4 v = acc[i][j];
      ushort4 pk;
      pk.x = f2bf(fmaxf(v[0] + bi.x, 0.f));
      pk.y = f2bf(fmaxf(v[1] + bi.y, 0.f));
      pk.z = f2bf(fmaxf(v[2] + bi.z, 0.f));
      pk.w = f2bf(fmaxf(v[3] + bi.w, 0.f));
      *(ushort4*)(hT + ((size_t)(b0 + bz)*N_ + n)*1536 + o4) = pk;
    }
  }
}

// ---------------- GEMM2f (bf16 MFMA): f[b][d][n] = cf_w2 @ h1 + b2 ----------------
// A = W2bf rows 0..127 (stride 512), B = hT[n][0..511], 128x128 tile, K=512
__global__ __launch_bounds__(256) void k_gemm2f(
    const ushort* __restrict__ W2bf, const ushort* __restrict__ hT,
    const float* __restrict__ cf_b2, float* __restrict__ f)
{
  const int bx = blockIdx.x;       // n tile (8)
  const int b  = blockIdx.y;       // batch
  const int t = threadIdx.x;
  const int wid = t >> 6, lane = t & 63;
  const int wr = wid >> 1, wc = wid & 1;
  __shared__ ushort Abuf[128*64];
  __shared__ ushort Bbuf[128*64];
  f32x4 acc[4][4];
  const f32x4 z4 = {0.f, 0.f, 0.f, 0.f};
  #pragma unroll
  for (int i = 0; i < 4; i++)
    #pragma unroll
    for (int j = 0; j < 4; j++) acc[i][j] = z4;

  const ushort* gA[4]; const ushort* gB[4];
  ushort* lA[4]; ushort* lB[4];
  #pragma unroll
  for (int j = 0; j < 4; j++) {
    int idx = j*256 + t;
    int row = idx >> 3, ps = idx & 7;
    int s = ps ^ (row & 7);
    gA[j] = W2bf + (size_t)row*512 + s*8;
    gB[j] = hT + ((size_t)b*N_ + bx*128 + row)*1536 + s*8;
    lA[j] = &Abuf[(j*4 + wid)*512];
    lB[j] = &Bbuf[(j*4 + wid)*512];
  }

  for (int k0 = 0; k0 < 512; k0 += 64) {
    #pragma unroll
    for (int j = 0; j < 4; j++) {
      gload16(gA[j] + k0, lA[j]);
      gload16(gB[j] + k0, lB[j]);
    }
    __syncthreads();
    #pragma unroll
    for (int ks = 0; ks < 2; ks++) {
      short8_t a[4], bb[4];
      const int l15 = lane & 15, lg = lane >> 4;
      #pragma unroll
      for (int i = 0; i < 4; i++) {
        int row = wr*64 + i*16 + l15;
        int slot = ks*4 + lg;
        a[i] = *(const short8_t*)&Abuf[row*64 + ((slot ^ (row & 7)) * 8)];
      }
      #pragma unroll
      for (int j = 0; j < 4; j++) {
        int row = wc*64 + j*16 + l15;
        int slot = ks*4 + lg;
        bb[j] = *(const short8_t*)&Bbuf[row*64 + ((slot ^ (row & 7)) * 8)];
      }
      #pragma unroll
      for (int i = 0; i < 4; i++)
        #pragma unroll
        for (int j = 0; j < 4; j++)
          acc[i][j] = __builtin_amdgcn_mfma_f32_16x16x32_bf16(a[i], bb[j], acc[i][j], 0, 0, 0);
    }
    __syncthreads();
  }
  const int lr = lane >> 4, lc = lane & 15;
  #pragma unroll
  for (int i = 0; i < 4; i++) {
    int d0 = wr*64 + i*16 + lr*4;
    float4 bi = *(const float4*)(cf_b2 + d0);
    float bia[4] = {bi.x, bi.y, bi.z, bi.w};
    #pragma unroll
    for (int j = 0; j < 4; j++) {
      int n = bx*128 + wc*64 + j*16 + lc;
      f32x4 v = acc[i][j];
      #pragma unroll
      for (int r = 0; r < 4; r++)
        f[((size_t)b*D_ + d0 + r)*N_ + n] = v[r] + bia[r];
    }
  }
}

// ---------------- GEMM2p (bf16 MFMA): p[b][k][n] = sum_e gw_e*(ex_w2_e @ eh_e) + bias
// A0/A1 = W2bf rows 128..255 (e0,e1), B0/B1 = hT[n][512..1023 / 1024..1535]
__global__ __launch_bounds__(256) void k_gemm2p(
    const ushort* __restrict__ W2bf, const ushort* __restrict__ hT,
    const float* __restrict__ ex_b2, const float* __restrict__ gw,
    float* __restrict__ p)
{
  const int bx = blockIdx.x;       // n tile (8)
  const int b  = blockIdx.y;
  const int t = threadIdx.x;
  const int wid = t >> 6, lane = t & 63;
  const int wr = wid >> 1, wc = wid & 1;
  __shared__ ushort A0[64*64], A1[64*64];
  __shared__ ushort B0[128*64], B1[128*64];
  f32x4 acc0[2][4], acc1[2][4];
  const f32x4 z4 = {0.f, 0.f, 0.f, 0.f};
  #pragma unroll
  for (int i = 0; i < 2; i++)
    #pragma unroll
    for (int j = 0; j < 4; j++) { acc0[i][j] = z4; acc1[i][j] = z4; }

  const ushort* W2p = W2bf + 65536;   // rows 128..255
  const ushort* gA0[2]; const ushort* gA1[2];
  const ushort* gB0[4]; const ushort* gB1[4];
  ushort *lA0[2], *lA1[2], *lB0[4], *lB1[4];
  #pragma unroll
  for (int j = 0; j < 2; j++) {
    int idx = j*256 + t;
    int row = idx >> 3, ps = idx & 7;
    int s = ps ^ (row & 7);
    gA0[j] = W2p + (size_t)row*512 + s*8;
    gA1[j] = W2p + (size_t)(64 + row)*512 + s*8;
    lA0[j] = &A0[(j*4 + wid)*512];
    lA1[j] = &A1[(j*4 + wid)*512];
  }
  #pragma unroll
  for (int j = 0; j < 4; j++) {
    int idx = j*256 + t;
    int row = idx >> 3, ps = idx & 7;
    int s = ps ^ (row & 7);
    gB0[j] = hT + ((size_t)b*N_ + bx*128 + row)*1536 + 512 + s*8;
    gB1[j] = hT + ((size_t)b*N_ + bx*128 + row)*1536 + 1024 + s*8;
    lB0[j] = &B0[(j*4 + wid)*512];
    lB1[j] = &B1[(j*4 + wid)*512];
  }

  for (int k0 = 0; k0 < 512; k0 += 64) {
    #pragma unroll
    for (int j = 0; j < 2; j++) {
      gload16(gA0[j] + k0, lA0[j]);
      gload16(gA1[j] + k0, lA1[j]);
    }
    #pragma unroll
    for (int j = 0; j < 4; j++) {
      gload16(gB0[j] + k0, lB0[j]);
      gload16(gB1[j] + k0, lB1[j]);
    }
    __syncthreads();
    #pragma unroll
    for (int ks = 0; ks < 2; ks++) {
      short8_t a0[2], a1[2], b0[4], b1[4];
      const int l15 = lane & 15, lg = lane >> 4;
      #pragma unroll
      for (int i = 0; i < 2; i++) {
        int row = wr*32 + i*16 + l15;
        int slot = ks*4 + lg;
        a0[i] = *(const short8_t*)&A0[row*64 + ((slot ^ (row & 7)) * 8)];
        a1[i] = *(const short8_t*)&A1[row*64 + ((slot ^ (row & 7)) * 8)];
      }
      #pragma unroll
      for (int j = 0; j < 4; j++) {
        int row = wc*64 + j*16 + l15;
        int slot = ks*4 + lg;
        b0[j] = *(const short8_t*)&B0[row*64 + ((slot ^ (row & 7)) * 8)];
        b1[j] = *(const short8_t*)&B1[row*64 + ((slot ^ (row & 7)) * 8)];
      }
      #pragma unroll
      for (int i = 0; i < 2; i++)
        #pragma unroll
        for (int j = 0; j < 4; j++) {
          acc0[i][j] = __builtin_amdgcn_mfma_f32_16x16x32_bf16(a0[i], b0[j], acc0[i][j], 0, 0, 0);
          acc1[i][j] = __builtin_amdgcn_mfma_f32_16x16x32_bf16(a1[i], b1[j], acc1[i][j], 0, 0, 0);
        }
    }
    __syncthreads();
  }
  const float gw0 = gw[b*2 + 0], gw1 = gw[b*2 + 1];
  const int lr = lane >> 4, lc = lane & 15;
  #pragma unroll
  for (int i = 0; i < 2; i++) {
    int kr0 = wr*32 + i*16 + lr*4;
    #pragma unroll
    for (int j = 0; j < 4; j++) {
      int n = bx*128 + wc*64 + j*16 + lc;
      f32x4 v0 = acc0[i][j], v1 = acc1[i][j];
      #pragma unroll
      for (int r = 0; r < 4; r++) {
        int kk = kr0 + r;
        float val = gw0*v0[r] + gw1*v1[r] + gw0*ex_b2[kk] + gw1*ex_b2[64 + kk];
        p[((size_t)b*K_ + kk)*N_ + n] = val;
      }
    }
  }
}

// ---------------- Sinkhorn (log-domain, 3 iters) + exp, in place on p ----------------
__global__ __launch_bounds__(1024) void k_sinkhorn(
    float* __restrict__ p, const float* __restrict__ dust)
{
  const int b = blockIdx.x;
  const int t = threadIdx.x;
  const int wid = t >> 6, lane = t & 63;
  __shared__ float u[65];
  __shared__ float v[N_];
  const float alpha = dust[0];
  const float NORM  = -logf((float)(K_ + N_));
  const float LOGNS = logf((float)N_);
  float* pb = p + (size_t)b*K_*N_;
  v[t] = 0.f;
  __syncthreads();
  for (int it = 0; it < 3; it++) {
    for (int k = wid; k < 65; k += 16) {
      const bool bin = (k == 64);
      float ml = -1e30f, sl = 0.f;
      for (int n = lane; n < N_; n += 64) {
        float z = (bin ? alpha : pb[(size_t)k*N_ + n]) + v[n];
        if (z > ml) { sl = sl * __expf(ml - z) + 1.f; ml = z; }
        else sl += __expf(z - ml);
      }
      for (int off = 32; off; off >>= 1) {
        float mo = __shfl_xor(ml, off);
        float so = __shfl_xor(sl, off);
        float mn = fmaxf(ml, mo);
        sl = sl * __expf(ml - mn) + so * __expf(mo - mn);
        ml = mn;
      }
      if (lane == 0) u[k] = (bin ? (LOGNS + NORM) : NORM) - (ml + __logf(sl));
    }
    __syncthreads();
    {
      float ml = -1e30f, sl = 0.f;
      for (int k = 0; k < 65; k++) {
        float z = ((k < 64) ? pb[(size_t)k*N_ + t] : alpha) + u[k];
        if (z > ml) { sl = sl * __expf(ml - z) + 1.f; ml = z; }
        else sl += __expf(z - ml);
      }
      v[t] = NORM - (ml + __logf(sl));
    }
    __syncthreads();
  }
  for (int k = 0; k < 64; k++) {
    float z = pb[(size_t)k*N_ + t];
    pb[(size_t)k*N_ + t] = __expf(z + u[k] + v[t] - NORM);
  }
}

// ---------------- aggmm: partial agg over n-chunk of 128 ----------------
// grid (8 nc, 16 b), 256 thr; pagg[b][nc][128 d][64 k]
__global__ __launch_bounds__(256) void k_aggmm(
    const float* __restrict__ f, const float* __restrict__ P,
    float* __restrict__ pagg)
{
  const int nc = blockIdx.x;
  const int b  = blockIdx.y;
  const int t  = threadIdx.x;
  __shared__ float fs[128][129];
  __shared__ float Ps[64][129];
  const float* fb = f + (size_t)b*D_*N_ + nc*128;
  const float* Pb = P + (size_t)b*K_*N_ + nc*128;
  #pragma unroll
  for (int pp = 0; pp < 16; pp++) {
    int flat = pp*256 + t;
    int row = flat >> 5, c4 = (flat & 31)*4;
    float4 v = *(const float4*)(fb + (size_t)row*N_ + c4);
    fs[row][c4+0] = v.x; fs[row][c4+1] = v.y; fs[row][c4+2] = v.z; fs[row][c4+3] = v.w;
  }
  #pragma unroll
  for (int pp = 0; pp < 8; pp++) {
    int flat = pp*256 + t;
    int row = flat >> 5, c4 = (flat & 31)*4;
    float4 v = *(const float4*)(Pb + (size_t)row*N_ + c4);
    Ps[row][c4+0] = v.x; Ps[row][c4+1] = v.y; Ps[row][c4+2] = v.z; Ps[row][c4+3] = v.w;
  }
  __syncthreads();
  const int td = t >> 3;        // 0..31 -> d base td*4
  const int tk = t & 7;         // 0..7  -> k base tk*8
  float acc[4][8] = {};
  #pragma unroll 4
  for (int nn = 0; nn < 128; nn++) {
    float fv[4], pv[8];
    #pragma unroll
    for (int i = 0; i < 4; i++) fv[i] = fs[td*4 + i][nn];
    #pragma unroll
    for (int j = 0; j < 8; j++) pv[j] = Ps[tk*8 + j][nn];
    #pragma unroll
    for (int i = 0; i < 4; i++)
      #pragma unroll
      for (int j = 0; j < 8; j++)
        acc[i][j] = fmaf(fv[i], pv[j], acc[i][j]);
  }
  float* ob = pagg + (((size_t)b*8 + nc)*128)*64;
  #pragma unroll
  for (int i = 0; i < 4; i++) {
    #pragma unroll
    for (int j = 0; j < 8; j += 4) {
      float4 v = {acc[i][j], acc[i][j+1], acc[i][j+2], acc[i][j+3]};
      *(float4*)(ob + (size_t)(td*4 + i)*64 + tk*8 + j) = v;
    }
  }
}

// ---------------- finish: reduce partials, norms, assemble ----------------
__global__ __launch_bounds__(1024) void k_finish(
    const float* __restrict__ pagg, const float* __restrict__ tt_g,
    float* __restrict__ out)
{
  const int b = blockIdx.x;
  const int t = threadIdx.x;
  const int wid = t >> 6, lane = t & 63;
  __shared__ float fs[128][65];
  __shared__ float Ps[64][65];
  __shared__ float invk[64];
  __shared__ float redw[16];
  __shared__ float redw2[16];
  __shared__ float tts[256];
  __shared__ float scal[2];
  if (t < 256) tts[t] = tt_g[b*T_ + t];
  // reduce 8 partials: thread handles d = t>>3, k = (t&7)*8 .. +8
  {
    const int d = t >> 3, k0 = (t & 7)*8;
    float4 s0 = {0,0,0,0}, s1 = {0,0,0,0};
    #pragma unroll
    for (int c = 0; c < 8; c++) {
      const float* src = pagg + (((size_t)b*8 + c)*128 + d)*64 + k0;
      float4 a = *(const float4*)(src);
      float4 bq = *(const float4*)(src + 4);
      s0.x += a.x; s0.y += a.y; s0.z += a.z; s0.w += a.w;
      s1.x += bq.x; s1.y += bq.y; s1.z += bq.z; s1.w += bq.w;
    }
    fs[d][k0+0] = s0.x; fs[d][k0+1] = s0.y; fs[d][k0+2] = s0.z; fs[d][k0+3] = s0.w;
    fs[d][k0+4] = s1.x; fs[d][k0+5] = s1.y; fs[d][k0+6] = s1.z; fs[d][k0+7] = s1.w;
  }
  __syncthreads();
  { int k = t & 63, dc = t >> 6;
    float s = 0.f;
    for (int d = dc*8; d < dc*8 + 8; d++) { float w = fs[d][k]; s = fmaf(w, w, s); }
    Ps[k][dc] = s; }
  __syncthreads();
  if (t < 64) {
    float s = 0.f;
    for (int dc = 0; dc < 16; dc++) s += Ps[t][dc];
    float inv = 1.f / fmaxf(sqrtf(s), 1e-12f);
    invk[t] = inv;
    Ps[t][16] = s * inv * inv;
  }
  __syncthreads();
  float p1 = 0.f, p2 = 0.f;
  if (t < 64)  p2 = Ps[t][16];
  if (t < T_)  { float w = tts[t]; p1 = w*w; }
  for (int off = 32; off; off >>= 1) { p1 += __shfl_down(p1, off); p2 += __shfl_down(p2, off); }
  if (lane == 0) { redw[wid] = p1; redw2[wid] = p2; }
  __syncthreads();
  if (t == 0) {
    float s1 = 0.f, s2 = 0.f;
    for (int w = 0; w < 16; w++) { s1 += redw[w]; s2 += redw2[w]; }
    float invT = 1.f / fmaxf(sqrtf(s1), 1e-12f);
    float tot  = s1*invT*invT + s2;
    float invG = 1.f / fmaxf(sqrtf(tot), 1e-12f);
    scal[0] = invG;
    scal[1] = invT * invG;
  }
  __syncthreads();
  const float invG = scal[0], invTG = scal[1];
  for (int idx = t; idx < OUTW; idx += 1024) {
    float vv;
    if (idx < T_) vv = tts[idx] * invTG;
    else { int r = idx - T_; int d = r >> 6, k = r & 63; vv = fs[d][k] * invk[k] * invG; }
    out[(size_t)b*OUTW + idx] = vv;
  }
}

extern "C" void kernel_launch(void* const* d_in, const int* in_sizes, int n_in,
                              void* d_out, int out_size, void* d_ws, size_t ws_size,
                              hipStream_t stream)
{
  const float* x_feat = (const float*)d_in[0];
  const float* token  = (const float*)d_in[1];
  const float* cf_w1  = (const float*)d_in[2];
  const float* cf_b1  = (const float*)d_in[3];
  const float* cf_w2  = (const float*)d_in[4];
  const float* cf_b2  = (const float*)d_in[5];
  const float* tf_w1  = (const float*)d_in[6];
  const float* tf_b1  = (const float*)d_in[7];
  const float* tf_w2  = (const float*)d_in[8];
  const float* tf_b2  = (const float*)d_in[9];
  const float* ex_w1  = (const float*)d_in[10];
  const float* ex_b1  = (const float*)d_in[11];
  const float* ex_w2  = (const float*)d_in[12];
  const float* ex_b2  = (const float*)d_in[13];
  const float* g_w1   = (const float*)d_in[14];
  const float* g_b1   = (const float*)d_in[15];
  const float* g_w2   = (const float*)d_in[16];
  const float* g_b2   = (const float*)d_in[17];
  const float* dust   = (const float*)d_in[18];
  float* out = (float*)d_out;

  char* ws = (char*)d_ws;
  float*  tt   = (float*)(ws + 0);            // 16 KB
  float*  gw   = (float*)(ws + 65536);        // 128 B
  float*  th1  = (float*)(ws + 131072);       // 32 KB
  float*  gh   = (float*)(ws + 262144);       // 8 KB
  ushort* Wbf  = (ushort*)(ws + 524288);      // 4.5 MB  (ends 5,242,880)
  ushort* W2bf = (ushort*)(ws + 5242880);     // 256 KB  (ends 5,505,024)
  ushort* xT   = (ushort*)(ws + 8388608);     // 24 MB (8 batches), dead after gemm1
  ushort* hT   = (ushort*)(ws + 33554432);    // 48 MB  (ends 83,886,080)
  float*  f    = (float*)(ws + 8388608);      // 8 MB, aliases dead xT
  float*  p    = (float*)(ws + 16777216);     // 4 MB
  float*  pagg = (float*)(ws + 25165824);     // 4 MB  (ends 29,360,128)

  k_prep_w<<<dim3(1152), dim3(256), 0, stream>>>(cf_w1, ex_w1, Wbf);
  k_prep_w2<<<dim3(64), dim3(256), 0, stream>>>(cf_w2, ex_w2, W2bf);
  k_token_a<<<dim3(160, 16), dim3(256), 0, stream>>>(token, tf_w1, tf_b1, g_w1, g_b1, th1, gh);
  k_token_b<<<dim3(65, 16), dim3(256), 0, stream>>>(th1, gh, tf_w2, tf_b2, g_w2, g_b2, tt, gw);
  for (int ph = 0; ph < 2; ph++) {
    k_prep_x<<<dim3(16, 24, 8), dim3(256), 0, stream>>>(x_feat, xT, ph*8);
    k_gemm1<<<dim3(8, 12, 8), dim3(256), 0, stream>>>(Wbf, xT, cf_b1, ex_b1, hT, ph*8);
  }
  k_gemm2f<<<dim3(8, 16), dim3(256), 0, stream>>>(W2bf, hT, cf_b2, f);
  k_gemm2p<<<dim3(8, 16), dim3(256), 0, stream>>>(W2bf, hT, ex_b2, gw, p);
  k_sinkhorn<<<dim3(16), dim3(1024), 0, stream>>>(p, dust);
  k_aggmm<<<dim3(8, 16), dim3(256), 0, stream>>>(f, p, pagg);
  k_finish<<<dim3(16), dim3(1024), 0, stream>>>(pagg, tt, out);
}